// Round 1
// baseline (4557.547 us; speedup 1.0000x reference)
//
#include <hip/hip_runtime.h>
#include <math.h>

#define NROWS   65536
#define OBS     512
#define HDIM    1024
#define OUTD    64
#define KCODES  10
#define CHUNK   16384
#define NCHUNK  4
#define LOG2PI_F 1.8378770664093453f

// ---------------------------------------------------------------------------
// Generic fp32 GEMM:  C[M,N] = EPI( A[M,K] @ W[K,N] + bias (+ prop[row]*wlast[col]) )
// BM=128, BN=64, BK=16, 256 threads, 8x4 accumulators per thread.
// EPI: 0 = none, 1 = tanh, 2 = relu, 3 = tanh(relu(x))
// ---------------------------------------------------------------------------
template<int EPI, int RANK1>
__global__ __launch_bounds__(256) void gemm_ep(
    const float* __restrict__ A, const float* __restrict__ W,
    const float* __restrict__ bias, float* __restrict__ C,
    int M, int N, int K,
    const float* __restrict__ prop, const float* __restrict__ wlast)
{
    __shared__ __attribute__((aligned(16))) float As[16][132];
    __shared__ __attribute__((aligned(16))) float Bs[16][64];

    const int tid = threadIdx.x;
    const int tx = tid & 15;        // 16 col-groups of 4
    const int ty = tid >> 4;        // 16 row-groups of 8
    const int bx = blockIdx.x;
    const int by = blockIdx.y;

    float acc[8][4];
#pragma unroll
    for (int i = 0; i < 8; ++i)
#pragma unroll
        for (int j = 0; j < 4; ++j) acc[i][j] = 0.0f;

    // global->LDS staging mapping
    const int arow = tid >> 1;              // 0..127
    const int ak   = (tid & 1) * 8;         // 0 or 8
    const float* Aptr = A + (size_t)(by * 128 + arow) * K + ak;
    const int brow = ty;                    // 0..15
    const int bcol = tx * 4;
    const float* Wptr = W + (size_t)brow * N + bx * 64 + bcol;

    for (int k0 = 0; k0 < K; k0 += 16) {
        float4 a0 = *(const float4*)(Aptr + k0);
        float4 a1 = *(const float4*)(Aptr + k0 + 4);
        float4 bv = *(const float4*)(Wptr + (size_t)k0 * N);

        As[ak + 0][arow] = a0.x;  As[ak + 1][arow] = a0.y;
        As[ak + 2][arow] = a0.z;  As[ak + 3][arow] = a0.w;
        As[ak + 4][arow] = a1.x;  As[ak + 5][arow] = a1.y;
        As[ak + 6][arow] = a1.z;  As[ak + 7][arow] = a1.w;
        *(float4*)&Bs[brow][bcol] = bv;
        __syncthreads();

#pragma unroll
        for (int k = 0; k < 16; ++k) {
            float4 av0 = *(const float4*)&As[k][ty * 8];
            float4 av1 = *(const float4*)&As[k][ty * 8 + 4];
            float4 b   = *(const float4*)&Bs[k][tx * 4];
            float av[8] = {av0.x, av0.y, av0.z, av0.w, av1.x, av1.y, av1.z, av1.w};
            float bb[4] = {b.x, b.y, b.z, b.w};
#pragma unroll
            for (int i = 0; i < 8; ++i)
#pragma unroll
                for (int j = 0; j < 4; ++j)
                    acc[i][j] = fmaf(av[i], bb[j], acc[i][j]);
        }
        __syncthreads();
    }

    // epilogue
    const int colg = bx * 64 + tx * 4;
    const int rowg = by * 128 + ty * 8;
    float4 bb = *(const float4*)(bias + colg);
    float4 wl = make_float4(0.f, 0.f, 0.f, 0.f);
    if (RANK1) wl = *(const float4*)(wlast + colg);

#pragma unroll
    for (int i = 0; i < 8; ++i) {
        const int r = rowg + i;
        float p = 0.0f;
        if (RANK1) p = prop[r];
        float v[4];
#pragma unroll
        for (int j = 0; j < 4; ++j) {
            float x = acc[i][j] + ((const float*)&bb)[j];
            if (RANK1) x += p * ((const float*)&wl)[j];
            if (EPI == 1) x = tanhf(x);
            else if (EPI == 2) x = fmaxf(x, 0.0f);
            else if (EPI == 3) x = (x > 0.0f) ? tanhf(x) : 0.0f;
            v[j] = x;
        }
        float4 o = make_float4(v[0], v[1], v[2], v[3]);
        *(float4*)(C + (size_t)r * N + colg) = o;
    }
}

// ---------------------------------------------------------------------------
// recon_table[10][512]: postnet + VQDecoder applied to each codebook row
// ---------------------------------------------------------------------------
__global__ __launch_bounds__(512) void k_table(
    const float* __restrict__ cb, const float* __restrict__ pw,
    const float* __restrict__ pb, const float* __restrict__ dw1,
    const float* __restrict__ db1, const float* __restrict__ dw2,
    const float* __restrict__ db2, float* __restrict__ table)
{
    __shared__ float cbr[OBS];
    __shared__ float post[HDIM];
    __shared__ float t1[128];
    const int c = blockIdx.x;
    const int tid = threadIdx.x;

    cbr[tid] = cb[c * OBS + tid];
    __syncthreads();

    // post = cbr @ postnet_w + postnet_b   (each thread: 2 cols)
    for (int j = tid; j < HDIM; j += 512) {
        float acc = pb[j];
        for (int k = 0; k < OBS; ++k) acc = fmaf(cbr[k], pw[(size_t)k * HDIM + j], acc);
        post[j] = acc;
    }
    __syncthreads();

    // t1 = tanh(post @ dec_w1 + db1)  (100 cols)
    if (tid < 100) {
        float acc = db1[tid];
        for (int k = 0; k < HDIM; ++k) acc = fmaf(post[k], dw1[(size_t)k * 100 + tid], acc);
        t1[tid] = tanhf(acc);
    }
    __syncthreads();

    // recon = tanh(t1 @ dec_w2 + db2)
    {
        float acc = db2[tid];
        for (int j = 0; j < 100; ++j) acc = fmaf(t1[j], dw2[(size_t)j * OBS + tid], acc);
        table[c * OBS + tid] = tanhf(acc);
    }
}

// ---------------------------------------------------------------------------
// quantize: per-row argmin over 10 codes; writes proposal (float) and
// accumulates sum of winning squared distances (== vq_mse * B * OBS)
// ---------------------------------------------------------------------------
__global__ __launch_bounds__(256) void k_quant(
    const float* __restrict__ enc, const float* __restrict__ cb,
    float* __restrict__ prop_out, double* __restrict__ vq_sum, int rows)
{
    __shared__ __attribute__((aligned(16))) float cbl[KCODES * OBS];
    const int tid = threadIdx.x;
    for (int i = tid; i < KCODES * OBS; i += 256) cbl[i] = cb[i];
    __syncthreads();

    const int lane = tid & 63;
    const int wv = (blockIdx.x * 256 + tid) >> 6;
    const int nw = (gridDim.x * 256) >> 6;
    double local = 0.0;

    for (int r = wv; r < rows; r += nw) {
        const float* e = enc + (size_t)r * OBS + lane * 8;
        float4 e0 = *(const float4*)e;
        float4 e1 = *(const float4*)(e + 4);
        double d[KCODES];
#pragma unroll
        for (int c = 0; c < KCODES; ++c) {
            const float* cp = &cbl[c * OBS + lane * 8];
            float4 c0 = *(const float4*)cp;
            float4 c1 = *(const float4*)(cp + 4);
            double s = 0.0;
            float dx;
            dx = e0.x - c0.x; s += (double)dx * dx;
            dx = e0.y - c0.y; s += (double)dx * dx;
            dx = e0.z - c0.z; s += (double)dx * dx;
            dx = e0.w - c0.w; s += (double)dx * dx;
            dx = e1.x - c1.x; s += (double)dx * dx;
            dx = e1.y - c1.y; s += (double)dx * dx;
            dx = e1.z - c1.z; s += (double)dx * dx;
            dx = e1.w - c1.w; s += (double)dx * dx;
            d[c] = s;
        }
#pragma unroll
        for (int c = 0; c < KCODES; ++c)
            for (int m = 1; m < 64; m <<= 1) d[c] += __shfl_xor(d[c], m);
        int best = 0;
#pragma unroll
        for (int c = 1; c < KCODES; ++c)
            if (d[c] < d[best]) best = c;   // strict < : first-min, matches argmin
        if (lane == 0) {
            prop_out[r] = (float)best;
            local += d[best];
        }
    }
    if (lane == 0) atomicAdd(vq_sum, local);
}

// ---------------------------------------------------------------------------
// recons_loss partial: sum over (Delta_X - recon_table[proposal])^2
// ---------------------------------------------------------------------------
__global__ __launch_bounds__(256) void k_recons(
    const float* __restrict__ dxm, const float* __restrict__ table,
    const float* __restrict__ prop, double* __restrict__ out_sum, int rows)
{
    __shared__ __attribute__((aligned(16))) float tb[KCODES * OBS];
    const int tid = threadIdx.x;
    for (int i = tid; i < KCODES * OBS; i += 256) tb[i] = table[i];
    __syncthreads();

    const int lane = tid & 63;
    const int wv = (blockIdx.x * 256 + tid) >> 6;
    const int nw = (gridDim.x * 256) >> 6;
    double local = 0.0;

    for (int r = wv; r < rows; r += nw) {
        const int p = (int)prop[r];
        const float* d = dxm + (size_t)r * OBS + lane * 8;
        const float* tp = &tb[p * OBS + lane * 8];
        float4 d0 = *(const float4*)d;
        float4 d1 = *(const float4*)(d + 4);
        float4 t0 = *(const float4*)tp;
        float4 t1 = *(const float4*)(tp + 4);
        float dv;
        dv = d0.x - t0.x; local += (double)dv * dv;
        dv = d0.y - t0.y; local += (double)dv * dv;
        dv = d0.z - t0.z; local += (double)dv * dv;
        dv = d0.w - t0.w; local += (double)dv * dv;
        dv = d1.x - t1.x; local += (double)dv * dv;
        dv = d1.y - t1.y; local += (double)dv * dv;
        dv = d1.z - t1.z; local += (double)dv * dv;
        dv = d1.w - t1.w; local += (double)dv * dv;
    }
    for (int m = 1; m < 64; m <<= 1) local += __shfl_xor(local, m);
    if (lane == 0) atomicAdd(out_sum, local);
}

// ---------------------------------------------------------------------------
// Normal log-prob row reduction: recon_loss = -sum_j(-0.5 z^2 - ls - 0.5 log2pi)
// ---------------------------------------------------------------------------
__global__ __launch_bounds__(256) void k_logprob(
    const float* __restrict__ mu, const float* __restrict__ Aact,
    const float* __restrict__ log_std, float* __restrict__ rl_out, int rows)
{
    const int tid = threadIdx.x;
    const int lane = tid & 63;
    const int wv = (blockIdx.x * 256 + tid) >> 6;
    const int nw = (gridDim.x * 256) >> 6;
    const float ls = log_std[lane];
    const float inv = expf(-ls);

    for (int r = wv; r < rows; r += nw) {
        const float m = mu[(size_t)r * OUTD + lane];
        const float a = Aact[(size_t)r * OUTD + lane];
        const float z = (a - m) * inv;
        float t = -0.5f * z * z - ls - 0.5f * LOG2PI_F;
        for (int s = 1; s < 64; s <<= 1) t += __shfl_xor(t, s);
        if (lane == 0) rl_out[r] = -t;
    }
}

// ---------------------------------------------------------------------------
__global__ void k_final(const float* __restrict__ rl, float* __restrict__ loss,
                        float* __restrict__ vt_out, const double* __restrict__ scal)
{
    const int i = blockIdx.x * blockDim.x + threadIdx.x;
    const double denom = (double)NROWS * (double)OBS;
    const float vt = (float)(scal[1] / denom + 2.0 * (scal[0] / denom));
    if (i < NROWS) loss[i] = rl[i] * vt;
    if (i == 0) *vt_out = vt;
}

__global__ void k_copyX(const float* __restrict__ src, float* __restrict__ dst)
{
    const size_t n4 = (size_t)NROWS * OBS / 4;
    const float4* s = (const float4*)src;
    float4* d = (float4*)dst;
    for (size_t i = blockIdx.x * blockDim.x + threadIdx.x; i < n4;
         i += (size_t)gridDim.x * blockDim.x)
        d[i] = s[i];
}

__global__ void k_zero(double* s)
{
    if (threadIdx.x < 2) s[threadIdx.x] = 0.0;
}

// ---------------------------------------------------------------------------
extern "C" void kernel_launch(void* const* d_in, const int* in_sizes, int n_in,
                              void* d_out, int out_size, void* d_ws, size_t ws_size,
                              hipStream_t stream)
{
    const float* X        = (const float*)d_in[0];
    const float* DX       = (const float*)d_in[1];
    const float* Aact     = (const float*)d_in[2];
    const float* enc_w1   = (const float*)d_in[4];
    const float* enc_b1   = (const float*)d_in[5];
    const float* enc_w2   = (const float*)d_in[6];
    const float* enc_b2   = (const float*)d_in[7];
    const float* prenet_w = (const float*)d_in[8];
    const float* prenet_b = (const float*)d_in[9];
    const float* codebook = (const float*)d_in[10];
    const float* postnet_w= (const float*)d_in[11];
    const float* postnet_b= (const float*)d_in[12];
    const float* dec_w1   = (const float*)d_in[13];
    const float* dec_b1   = (const float*)d_in[14];
    const float* dec_w2   = (const float*)d_in[15];
    const float* dec_b2   = (const float*)d_in[16];
    const float* a_w1     = (const float*)d_in[17];
    const float* a_b1     = (const float*)d_in[18];
    const float* a_w2     = (const float*)d_in[19];
    const float* a_b2     = (const float*)d_in[20];
    const float* a_w3     = (const float*)d_in[21];
    const float* a_b3     = (const float*)d_in[22];
    const float* a_w4     = (const float*)d_in[23];
    const float* a_b4     = (const float*)d_in[24];
    const float* log_std  = (const float*)d_in[25];

    // workspace layout
    char* ws = (char*)d_ws;
    double* scal   = (double*)ws;                 // [0]=vq_sum, [1]=recons_sum
    float*  table  = (float*)(ws + 256);          // 10*512 floats
    const size_t MB = (size_t)1 << 20;
    float* c_h   = (float*)(ws + 1 * MB);         // CHUNK*512  (32MB)  h / m1 / unused
    float* c_mid = (float*)(ws + 34 * MB);        // CHUNK*1024 (64MB)  mid / m2
    float* c_enc = (float*)(ws + 99 * MB);        // CHUNK*512  (32MB)  enc_out / m3
    float* c_mu  = (float*)(ws + 132 * MB);       // CHUNK*64   (4MB)

    // output layout (flat concat, float32)
    float* out    = (float*)d_out;
    float* o_loss = out;                               // [B]
    float* o_rl   = out + NROWS;                       // [B]
    float* o_X    = out + 2 * NROWS;                   // [B,512]
    float* o_prop = out + 2 * NROWS + (size_t)NROWS * OBS;      // [B]
    float* o_vt   = o_prop + NROWS;                    // [1]

    k_zero<<<1, 64, 0, stream>>>(scal);
    k_table<<<KCODES, 512, 0, stream>>>(codebook, postnet_w, postnet_b,
                                        dec_w1, dec_b1, dec_w2, dec_b2, table);

    for (int c = 0; c < NCHUNK; ++c) {
        const size_t r0 = (size_t)c * CHUNK;
        const float* dxc = DX + r0 * OBS;
        const float* xc  = X + r0 * OBS;
        float* propc = o_prop + r0;

        dim3 gN512(OBS / 64, CHUNK / 128);   // (8,128)
        dim3 gN1024(HDIM / 64, CHUNK / 128); // (16,128)
        dim3 gN64(1, CHUNK / 128);

        // enc: h = tanh(DX @ enc_w1 + b1)
        gemm_ep<1, 0><<<gN512, 256, 0, stream>>>(dxc, enc_w1, enc_b1, c_h,
                                                 CHUNK, 512, OBS, nullptr, nullptr);
        // mid = h @ enc_w2 + b2
        gemm_ep<0, 0><<<gN1024, 256, 0, stream>>>(c_h, enc_w2, enc_b2, c_mid,
                                                  CHUNK, HDIM, 512, nullptr, nullptr);
        // enc_out = mid @ prenet_w + prenet_b
        gemm_ep<0, 0><<<gN512, 256, 0, stream>>>(c_mid, prenet_w, prenet_b, c_enc,
                                                 CHUNK, OBS, HDIM, nullptr, nullptr);
        // quantize
        k_quant<<<512, 256, 0, stream>>>(c_enc, codebook, propc, scal + 0, CHUNK);
        // recons partial
        k_recons<<<512, 256, 0, stream>>>(dxc, table, propc, scal + 1, CHUNK);
        // actor
        gemm_ep<2, 1><<<gN512, 256, 0, stream>>>(xc, a_w1, a_b1, c_h,
                                                 CHUNK, 512, OBS, propc, a_w1 + 512 * 512);
        gemm_ep<2, 0><<<gN512, 256, 0, stream>>>(c_h, a_w2, a_b2, c_mid,
                                                 CHUNK, 512, 512, nullptr, nullptr);
        gemm_ep<3, 0><<<gN512, 256, 0, stream>>>(c_mid, a_w3, a_b3, c_enc,
                                                 CHUNK, 512, 512, nullptr, nullptr);
        gemm_ep<0, 0><<<gN64, 256, 0, stream>>>(c_enc, a_w4, a_b4, c_mu,
                                                CHUNK, OUTD, 512, nullptr, nullptr);
        k_logprob<<<512, 256, 0, stream>>>(c_mu, Aact + r0 * OUTD, log_std,
                                           o_rl + r0, CHUNK);
    }

    k_final<<<NROWS / 256, 256, 0, stream>>>(o_rl, o_loss, o_vt, scal);
    k_copyX<<<2048, 256, 0, stream>>>(X, o_X);
}